// Round 11
// baseline (517.855 us; speedup 1.0000x reference)
//
#include <hip/hip_runtime.h>
#include <hip/hip_bf16.h>
#include <math.h>

typedef __attribute__((ext_vector_type(8))) short short8;
typedef __attribute__((ext_vector_type(4))) float floatx4;

#define LRELU_S 0.2f
#define HALF_LOG_2PI 0.91893853320467274178f

__device__ __forceinline__ short f2bf(float f) {
  union { float f; unsigned u; } x; x.f = f;
  unsigned r = x.u + 0x7FFFu + ((x.u >> 16) & 1u);
  return (short)(r >> 16);
}
__device__ __forceinline__ float lrelu(float v) { return v > 0.f ? v : LRELU_S * v; }
__device__ __forceinline__ float frcp(float v) { return __builtin_amdgcn_rcpf(v); }
__device__ __forceinline__ float ftanh(float x) {
  float e = __expf(2.f * x);
  return 1.f - 2.f * frcp(e + 1.f);
}
__device__ __forceinline__ int swzb(int row) {
  return ((((row >> 2) & 3) << 1) | (row & 1)) << 4;
}

// ============ fused preamble: deg-count | wconv | layer3 node-gemm ============
__global__ __launch_bounds__(256) void k_pre(const int* __restrict__ ei,
    int* __restrict__ degF, int* __restrict__ degR, int E,
    const float* __restrict__ x, const float* __restrict__ nd,
    const float* __restrict__ Wl3, const float* __restrict__ Wr3,
    float* __restrict__ XL, float* __restrict__ XR, int n,
    const float* __restrict__ Wfc, const float* __restrict__ Wfc1,
    const float* __restrict__ Wmu, const float* __restrict__ Wstd,
    short* __restrict__ WBF, int nbE, int nbW, int nbG) {
  __shared__ float sx[32][65];
  int b = blockIdx.x;
  if (b < nbE) {
    int e = b * 256 + threadIdx.x;
    if (e < E) {
      int a = ei[e], bb = ei[E + e];
      atomicAdd(degF + bb, 1);
      atomicAdd(degR + a, 1);
    }
  } else if (b < nbE + nbW) {
    int t = (b - nbE) * 256 + threadIdx.x;
    if (t < 270336) {
      int tile = t >> 9, pos = t & 511;
      int lane = pos >> 3, j = pos & 7;
      int lr = lane & 15, lg = lane >> 4;
      float v;
      if (tile < 256) {
        int nt = tile >> 3, kk = tile & 7;
        v = Wfc[(nt * 16 + lr) * 256 + kk * 32 + lg * 8 + j];
      } else if (tile < 512) {
        int t2 = tile - 256;
        int nt = t2 >> 4, kk = t2 & 15;
        v = Wfc1[(nt * 16 + lr) * 512 + kk * 32 + lg * 8 + j];
      } else {
        int t3 = tile - 512;
        int nt = t3 >> 3, kk = t3 & 7;
        int r = nt * 16 + lr;
        int col = kk * 32 + lg * 8 + j;
        v = (r < 16) ? Wmu[r * 256 + col] : Wstd[(r - 16) * 256 + col];
      }
      WBF[t] = f2bf(v);
    }
  } else {
    // layer-3 node gemm: [x|nd] @ (Wl3|Wr3)^T -> XL/XR [n,128]
    int r = b - nbE - nbW;
    int sel = (r >= nbG) ? 1 : 0;
    int bx = r - sel * nbG;
    const float* __restrict__ W = sel ? Wr3 : Wl3;
    float* __restrict__ out = sel ? XR : XL;
    const int row0 = bx * 32;
    const int tid = threadIdx.x;
    for (int i = tid; i < 32 * 64; i += 256) {
      int rr = i >> 6, c = i & 63;
      int row = row0 + rr;
      float v = 0.f;
      if (row < n) v = (c < 63) ? x[row * 63 + c] : nd[row];
      sx[rr][c] = v;
    }
    __syncthreads();
    const int nl = tid & 31;
    const int fg = tid >> 5;
    const int row = row0 + nl;
    if (row >= n) return;
    for (int i = 0; i < 16; i++) {
      int f = fg * 16 + i;
      const float* __restrict__ wrow = W + (size_t)f * 64;
      float acc = 0.f;
      #pragma unroll
      for (int k = 0; k < 64; k += 4) {
        float4 wv = *(const float4*)(wrow + k);
        acc += sx[nl][k] * wv.x + sx[nl][k + 1] * wv.y
             + sx[nl][k + 2] * wv.z + sx[nl][k + 3] * wv.w;
      }
      out[(size_t)row * 128 + f] = acc;
    }
  }
}

// ============ parallel scan (2 blocks x 1024 threads, one per direction) ============
__global__ __launch_bounds__(1024) void k_scan2(const int* __restrict__ degF,
    int* __restrict__ startF, int* __restrict__ curF, int* __restrict__ csrF,
    const int* __restrict__ degR, int* __restrict__ startR, int* __restrict__ curR,
    int* __restrict__ csrR, int n) {
  const int* __restrict__ deg = blockIdx.x ? degR : degF;
  int* __restrict__ start = blockIdx.x ? startR : startF;
  int* __restrict__ cur   = blockIdx.x ? curR : curF;
  int* __restrict__ csr   = blockIdx.x ? csrR : csrF;
  __shared__ int wsum[16];
  int t = threadIdx.x;
  int chunk = (n + 1023) >> 10;
  int lo = t * chunk; if (lo > n) lo = n;
  int hi = lo + chunk; if (hi > n) hi = n;
  int s = 0;
  for (int i = lo; i < hi; i++) s += deg[i] + 1;
  int lane = t & 63, wv = t >> 6;
  int inc = s;
  #pragma unroll
  for (int o = 1; o < 64; o <<= 1) {
    int v = __shfl_up(inc, o, 64);
    if (lane >= o) inc += v;
  }
  if (lane == 63) wsum[wv] = inc;
  __syncthreads();
  if (t < 64) {
    int v = (t < 16) ? wsum[t] : 0;
    #pragma unroll
    for (int o = 1; o < 16; o <<= 1) {
      int u = __shfl_up(v, o, 64);
      if (t >= o) v += u;
    }
    if (t < 16) wsum[t] = v;      // inclusive per-wave prefix
  }
  __syncthreads();
  int base = (wv ? wsum[wv - 1] : 0) + (inc - s);
  if (t == 0) start[n] = wsum[15];
  int acc = base;
  for (int i = lo; i < hi; i++) {
    start[i] = acc; cur[i] = acc;
    acc += deg[i] + 1;
    csr[acc - 1] = i;             // self-loop slot at segment end
  }
}

__global__ __launch_bounds__(256) void k_scatter(const int* __restrict__ ei,
    int* __restrict__ curF, int* __restrict__ curR,
    int* __restrict__ csrF, int* __restrict__ csrR, int E) {
  int e = blockIdx.x * 256 + threadIdx.x;
  if (e >= E) return;
  int a = ei[e], b = ei[E + e];
  int pf = atomicAdd(curF + b, 1); csrF[pf] = a;
  int pr = atomicAdd(curR + a, 1); csrR[pr] = b;
}

// ============ node gemm ============
template<int K, int F>
__global__ __launch_bounds__(256) void k_node_gemm(const float* __restrict__ in,
    const float* __restrict__ Wl, const float* __restrict__ Wr,
    float* __restrict__ xl, float* __restrict__ xr, int n) {
  __shared__ float sx[32][K + 1];
  const int row0 = blockIdx.x * 32;
  const float* __restrict__ W = blockIdx.y ? Wr : Wl;
  float* __restrict__ out = blockIdx.y ? xr : xl;
  const int tid = threadIdx.x;
  for (int i = tid; i < 32 * K; i += 256) {
    int r = i / K, c = i - r * K;
    sx[r][c] = (row0 + r < n) ? in[(size_t)(row0 + r) * K + c] : 0.f;
  }
  __syncthreads();
  const int nl = tid & 31;
  const int fg = tid >> 5;
  const int row = row0 + nl;
  if (row >= n) return;
  constexpr int FP = F / 8;
  for (int i = 0; i < FP; i++) {
    int f = fg * FP + i;
    const float* __restrict__ wrow = W + (size_t)f * K;
    float acc = 0.f;
    #pragma unroll
    for (int k = 0; k < K; k += 4) {
      float4 wv = *(const float4*)(wrow + k);
      acc += sx[nl][k] * wv.x + sx[nl][k + 1] * wv.y
           + sx[nl][k + 2] * wv.z + sx[nl][k + 3] * wv.w;
    }
    out[(size_t)row * F + f] = acc;
  }
}

// ============ fused GATv2 edge pass, 4 feat/thread, 2 neighbors/iter ============
// OM: 0 = f32 out only, 1 = f32 + bf16(SBF), 2 = bf16(SBF) only
template<int HF, int C, int OM>
__global__ __launch_bounds__(256) void k_gat_fused(const float* __restrict__ XL,
    const float* __restrict__ XR, const float* __restrict__ att,
    const float* __restrict__ bias, const int* __restrict__ start,
    const int* __restrict__ csr, float* __restrict__ out,
    short* __restrict__ sout, int scol, int n) {
  constexpr int G = HF / 4;
  constexpr int DPB = 256 / G;
  int d = blockIdx.x * DPB + threadIdx.x / G;
  if (d >= n) return;
  int f4 = threadIdx.x & (G - 1);
  float4 xr = *(const float4*)(XR + (size_t)d * HF + f4 * 4);
  float4 av = *(const float4*)(att + f4 * 4);
  float4 bv = *(const float4*)(bias + f4 * 4);
  float m = -INFINITY, den = 0.f;
  float4 acc = {0.f, 0.f, 0.f, 0.f};
  int j0 = start[d], j1 = start[d + 1];   // deg >= 1 always (self loop)

  auto score = [&](const float4& xl) {
    float e0 = xl.x + xr.x; e0 = e0 > 0.f ? e0 : LRELU_S * e0;
    float e1 = xl.y + xr.y; e1 = e1 > 0.f ? e1 : LRELU_S * e1;
    float e2 = xl.z + xr.z; e2 = e2 > 0.f ? e2 : LRELU_S * e2;
    float e3 = xl.w + xr.w; e3 = e3 > 0.f ? e3 : LRELU_S * e3;
    float p = av.x * e0 + av.y * e1 + av.z * e2 + av.w * e3;
    #pragma unroll
    for (int o = C / 8; o > 0; o >>= 1) p += __shfl_xor(p, o, 64);
    return p;
  };

  int j = j0;
  for (; j + 1 < j1; j += 2) {
    int sa = csr[j], sb = csr[j + 1];
    float4 xla = *(const float4*)(XL + (size_t)sa * HF + f4 * 4);
    float4 xlb = *(const float4*)(XL + (size_t)sb * HF + f4 * 4);
    float sca = score(xla);
    float scb = score(xlb);
    float mn = fmaxf(fmaxf(m, sca), scb);      // v_max3
    float scale = __expf(m - mn);
    float pa = __expf(sca - mn);
    float pb = __expf(scb - mn);
    den = den * scale + pa + pb;
    acc.x = acc.x * scale + pa * xla.x + pb * xlb.x;
    acc.y = acc.y * scale + pa * xla.y + pb * xlb.y;
    acc.z = acc.z * scale + pa * xla.z + pb * xlb.z;
    acc.w = acc.w * scale + pa * xla.w + pb * xlb.w;
    m = mn;
  }
  if (j < j1) {
    int s = csr[j];
    float4 xl = *(const float4*)(XL + (size_t)s * HF + f4 * 4);
    float sc = score(xl);
    float mn = fmaxf(m, sc);
    float scale = __expf(m - mn);
    float p = __expf(sc - mn);
    den = den * scale + p;
    acc.x = acc.x * scale + p * xl.x;
    acc.y = acc.y * scale + p * xl.y;
    acc.z = acc.z * scale + p * xl.z;
    acc.w = acc.w * scale + p * xl.w;
    m = mn;
  }
  float inv = frcp(den + 1e-16f);
  float4 o4;
  o4.x = lrelu(acc.x * inv + bv.x);
  o4.y = lrelu(acc.y * inv + bv.y);
  o4.z = lrelu(acc.z * inv + bv.z);
  o4.w = lrelu(acc.w * inv + bv.w);
  if (OM != 2) *(float4*)(out + (size_t)d * HF + f4 * 4) = o4;
  if (OM != 0) {
    union { short s[4]; int2 v; } u;
    u.s[0] = f2bf(o4.x); u.s[1] = f2bf(o4.y);
    u.s[2] = f2bf(o4.z); u.s[3] = f2bf(o4.w);
    *(int2*)(sout + (size_t)d * 128 + scol + f4 * 4) = u.v;
  }
}

// ============ fused MLP head: 64 edges / block, 512 threads, chunked H1 ============
__device__ __forceinline__ short8 lds_frag(const char* base, int row, int strideB, int k0, int lg) {
  int off = row * strideB + (((k0 * 2) + lg * 16) ^ swzb(row));
  return *(const short8*)(base + off);
}

__global__ __launch_bounds__(512, 6) void k_head(
    const short* __restrict__ SBF, const short* __restrict__ WBF,
    const int* __restrict__ ei, const float* __restrict__ epsg,
    const float* __restrict__ b_fc, const float* __restrict__ b_fc1,
    const float* __restrict__ b_mu, const float* __restrict__ b_std,
    float* __restrict__ out, double* __restrict__ LP, int E) {
  __shared__ __align__(16) char lX[32768];    // X [64][256] bf16 swizzled; later H2
  __shared__ __align__(16) char cbuf[16384];  // H1 chunk [64][128] bf16; later lMS/lred
  float* lMS  = (float*)cbuf;                 // [64*32]
  float* lred = (float*)(cbuf + 8192);        // [8]

  const int tid = threadIdx.x;
  const int eg0 = blockIdx.x * 64;

  for (int q = tid; q < 2048; q += 512) {
    int le = q >> 5, c = q & 31;
    int eg = eg0 + le;
    int node = (c < 16) ? ei[eg] : ei[E + eg];
    const short* srcp = SBF + (size_t)node * 128 + (c & 15) * 8;
    int4 v = *(const int4*)srcp;
    int col = (c * 16) ^ swzb(le);
    *(int4*)(lX + le * 512 + col) = v;
  }
  __syncthreads();

  const int w = tid >> 6, lane = tid & 63;
  const int lr = lane & 15, lg = lane >> 4;
  const floatx4 zero = {0.f, 0.f, 0.f, 0.f};

  floatx4 acc2[2][4];
  #pragma unroll
  for (int a = 0; a < 2; a++)
    #pragma unroll
    for (int b = 0; b < 4; b++) acc2[a][b] = zero;

  for (int c = 0; c < 4; c++) {
    floatx4 acc1[4];
    #pragma unroll
    for (int mi = 0; mi < 4; mi++) acc1[mi] = zero;
    for (int kk = 0; kk < 8; kk++) {
      int tile = (c * 8 + w) * 8 + kk;
      short8 b = *(const short8*)(WBF + tile * 512 + lane * 8);
      #pragma unroll
      for (int mi = 0; mi < 4; mi++) {
        short8 a = lds_frag(lX, mi * 16 + lr, 512, kk * 32, lg);
        acc1[mi] = __builtin_amdgcn_mfma_f32_16x16x32_bf16(a, b, acc1[mi], 0, 0, 0);
      }
    }
    __syncthreads();
    {
      int cl = w * 16 + lr;
      float bv = b_fc[c * 128 + cl];
      #pragma unroll
      for (int mi = 0; mi < 4; mi++)
        #pragma unroll
        for (int j = 0; j < 4; j++) {
          int row = mi * 16 + lg * 4 + j;
          float v = acc1[mi][j] + bv;
          v = v > 0.f ? v : 0.f;
          *(short*)(cbuf + row * 256 + ((cl * 2) ^ swzb(row))) = f2bf(v);
        }
    }
    __syncthreads();

    for (int kk2 = 0; kk2 < 4; kk2++) {
      short8 a[4];
      #pragma unroll
      for (int mi = 0; mi < 4; mi++) a[mi] = lds_frag(cbuf, mi * 16 + lr, 256, kk2 * 32, lg);
      #pragma unroll
      for (int ni2 = 0; ni2 < 2; ni2++) {
        int tile = 256 + (2 * w + ni2) * 16 + (c * 4 + kk2);
        short8 b = *(const short8*)(WBF + tile * 512 + lane * 8);
        #pragma unroll
        for (int mi = 0; mi < 4; mi++)
          acc2[ni2][mi] = __builtin_amdgcn_mfma_f32_16x16x32_bf16(a[mi], b, acc2[ni2][mi], 0, 0, 0);
      }
    }
  }
  __syncthreads();

  #pragma unroll
  for (int ni2 = 0; ni2 < 2; ni2++) {
    int n = (2 * w + ni2) * 16 + lr;
    float bv = b_fc1[n];
    #pragma unroll
    for (int mi = 0; mi < 4; mi++)
      #pragma unroll
      for (int j = 0; j < 4; j++) {
        int row = mi * 16 + lg * 4 + j;
        float v = acc2[ni2][mi][j] + bv;
        v = v > 0.f ? v : 0.f;
        *(short*)(lX + row * 512 + ((n * 2) ^ swzb(row))) = f2bf(v);
      }
  }
  __syncthreads();

  {
    const int mfr = w >> 1, nfr = w & 1;
    floatx4 acc3 = zero;
    for (int kk = 0; kk < 8; kk++) {
      short8 a = lds_frag(lX, mfr * 16 + lr, 512, kk * 32, lg);
      int tile = 512 + nfr * 8 + kk;
      short8 b = *(const short8*)(WBF + tile * 512 + lane * 8);
      acc3 = __builtin_amdgcn_mfma_f32_16x16x32_bf16(a, b, acc3, 0, 0, 0);
    }
    int coln = nfr * 16 + lr;
    float bv = (coln < 16) ? b_mu[coln] : b_std[coln - 16];
    #pragma unroll
    for (int j = 0; j < 4; j++) {
      int row = mfr * 16 + lg * 4 + j;
      lMS[row * 32 + coln] = acc3[j] + bv;
    }
  }
  __syncthreads();

  float lpsum = 0.f;
  #pragma unroll
  for (int it = 0; it < 2; it++) {
    int idx = tid + it * 512;
    int m = idx >> 4, g = idx & 15;
    float mu = lMS[m * 32 + g];
    float sr = lMS[m * 32 + 16 + g];
    float sd = (sr > 20.f) ? sr : __logf(1.f + __expf(sr));
    int eg = eg0 + m;
    float ep = epsg[(size_t)eg * 16 + g];
    float action = mu + sd * ep;
    float ra = ftanh(action);
    out[(size_t)eg * 16 + g] = ra;
    lpsum += -0.5f * ep * ep - __logf(sd) - HALF_LOG_2PI - __logf(1.f - ra * ra + 1e-7f);
  }
  #pragma unroll
  for (int o = 32; o > 0; o >>= 1) lpsum += __shfl_xor(lpsum, o, 64);
  if (lane == 0) lred[w] = lpsum;
  __syncthreads();
  if (tid == 0) {
    double ssum = 0.0;
    #pragma unroll
    for (int i = 0; i < 8; i++) ssum += (double)lred[i];
    atomicAdd(LP, ssum);
  }
}

__global__ void k_finalize(const double* __restrict__ LP, float* __restrict__ out, int pos) {
  out[pos] = (float)(*LP);
}

// =====================================================================
extern "C" void kernel_launch(void* const* d_in, const int* in_sizes, int n_in,
                              void* d_out, int out_size, void* d_ws, size_t ws_size,
                              hipStream_t stream) {
  const float* x    = (const float*)d_in[0];
  const float* nd   = (const float*)d_in[1];
  const int*   ei   = (const int*)d_in[2];
  const float* epsg = (const float*)d_in[3];
  const float* Wl3 = (const float*)d_in[4];  const float* Wr3 = (const float*)d_in[5];
  const float* att3 = (const float*)d_in[6]; const float* b3 = (const float*)d_in[7];
  const float* Wl4 = (const float*)d_in[8];  const float* Wr4 = (const float*)d_in[9];
  const float* att4 = (const float*)d_in[10]; const float* b4 = (const float*)d_in[11];
  const float* Wl1 = (const float*)d_in[12]; const float* Wr1 = (const float*)d_in[13];
  const float* att1 = (const float*)d_in[14]; const float* b1 = (const float*)d_in[15];
  const float* Wl2 = (const float*)d_in[16]; const float* Wr2 = (const float*)d_in[17];
  const float* att2 = (const float*)d_in[18]; const float* b2 = (const float*)d_in[19];
  const float* W_fc  = (const float*)d_in[20]; const float* b_fc  = (const float*)d_in[21];
  const float* W_fc1 = (const float*)d_in[22]; const float* b_fc1 = (const float*)d_in[23];
  const float* W_mu  = (const float*)d_in[24]; const float* b_mu  = (const float*)d_in[25];
  const float* W_std = (const float*)d_in[26]; const float* b_std = (const float*)d_in[27];

  const int N = in_sizes[0] / 63;
  const int E = in_sizes[2] / 2;
  const int E2 = E + N;
  const size_t NN = (size_t)N;

  char* base = (char*)d_ws;
  auto alloc = [&](size_t bytes) { char* p = base; base += (bytes + 15) & ~(size_t)15; return p; };

  // degF, degR, LP contiguous -> single memset covers all three
  int* degF   = (int*)alloc(NN * 4);
  int* degR   = (int*)alloc(NN * 4);
  double* LPp = (double*)alloc(16);
  float* bufB = (float*)alloc(NN * 128 * 4);
  float* XL   = (float*)alloc(NN * 128 * 4);
  float* XR   = (float*)alloc(NN * 128 * 4);
  float* XBp  = (float*)alloc(NN * 64 * 4);
  int* curF   = (int*)alloc(NN * 4);
  int* curR   = (int*)alloc(NN * 4);
  int* startF = (int*)alloc((NN + 1) * 4);
  int* startR = (int*)alloc((NN + 1) * 4);
  int* csrF   = (int*)alloc((size_t)E2 * 4);
  int* csrR   = (int*)alloc((size_t)E2 * 4);
  short* SBF  = (short*)alloc(NN * 128 * 2);
  short* WBF  = (short*)alloc(270336 * 2);

  auto nb = [](int total) { return (total + 255) / 256; };
  const int nbE = nb(E), nbW = nb(270336), nbG = (N + 31) / 32;

  // zero degF+degR+LP in one shot
  hipMemsetAsync(degF, 0, NN * 8 + 16, stream);

  // fused preamble: deg | wconv | layer3 gemm ([x|nd] -> XL/XR)
  k_pre<<<nbE + nbW + 2 * nbG, 256, 0, stream>>>(ei, degF, degR, E,
      x, nd, Wl3, Wr3, XL, XR, N, W_fc, W_fc1, W_mu, W_std, WBF, nbE, nbW, nbG);
  k_scan2<<<2, 1024, 0, stream>>>(degF, startF, curF, csrF, degR, startR, curR, csrR, N);
  k_scatter<<<nbE, 256, 0, stream>>>(ei, curF, curR, csrF, csrR, E);

  // ---- gat3 (reverse): XL/XR -> bufB[N,128]
  k_gat_fused<128, 32, 0><<<(N + 7) / 8, 256, 0, stream>>>(XL, XR, att3, b3, startR, csrR, bufB, nullptr, 0, N);

  // ---- gemm4 + gat4 (reverse): bufB -> XB[N,64] (+ bf16 into SBF cols 64..127)
  { dim3 g(nbG, 2);
    k_node_gemm<128, 64><<<g, 256, 0, stream>>>(bufB, Wl4, Wr4, XL, XR, N); }
  k_gat_fused<64, 64, 1><<<(N + 15) / 16, 256, 0, stream>>>(XL, XR, att4, b4, startR, csrR, XBp, SBF, 64, N);

  // ---- gemm1 + gat1 (forward): XB -> bufB[N,128]
  { dim3 g(nbG, 2);
    k_node_gemm<64, 128><<<g, 256, 0, stream>>>(XBp, Wl1, Wr1, XL, XR, N); }
  k_gat_fused<128, 32, 0><<<(N + 7) / 8, 256, 0, stream>>>(XL, XR, att1, b1, startF, csrF, bufB, nullptr, 0, N);

  // ---- gemm2 + gat2 (forward): bufB -> bf16 SBF cols 0..63 only
  { dim3 g(nbG, 2);
    k_node_gemm<128, 64><<<g, 256, 0, stream>>>(bufB, Wl2, Wr2, XL, XR, N); }
  k_gat_fused<64, 64, 2><<<(N + 15) / 16, 256, 0, stream>>>(XL, XR, att2, b2, startF, csrF, nullptr, SBF, 0, N);

  // ---- head + finalize
  k_head<<<E / 64, 512, 0, stream>>>(SBF, WBF, ei, epsg, b_fc, b_fc1, b_mu, b_std,
                                     (float*)d_out, LPp, E);
  k_finalize<<<1, 1, 0, stream>>>(LPp, (float*)d_out, E * 16);
}

// Round 12
// 430.724 us; speedup vs baseline: 1.2023x; 1.2023x over previous
//
#include <hip/hip_runtime.h>
#include <hip/hip_bf16.h>
#include <math.h>

typedef __attribute__((ext_vector_type(8))) short short8;
typedef __attribute__((ext_vector_type(4))) float floatx4;

#define LRELU_S 0.2f
#define HALF_LOG_2PI 0.91893853320467274178f

__device__ __forceinline__ short f2bf(float f) {
  union { float f; unsigned u; } x; x.f = f;
  unsigned r = x.u + 0x7FFFu + ((x.u >> 16) & 1u);
  return (short)(r >> 16);
}
__device__ __forceinline__ float lrelu(float v) { return v > 0.f ? v : LRELU_S * v; }
__device__ __forceinline__ float frcp(float v) { return __builtin_amdgcn_rcpf(v); }
__device__ __forceinline__ float ftanh(float x) {
  float e = __expf(2.f * x);
  return 1.f - 2.f * frcp(e + 1.f);
}
__device__ __forceinline__ int swzb(int row) {
  return ((((row >> 2) & 3) << 1) | (row & 1)) << 4;
}

// ============ fused preamble: deg-count | wconv | layer3 node-gemm ============
__global__ __launch_bounds__(256) void k_pre(const int* __restrict__ ei,
    int* __restrict__ degF, int* __restrict__ degR, int E,
    const float* __restrict__ x, const float* __restrict__ nd,
    const float* __restrict__ Wl3, const float* __restrict__ Wr3,
    float* __restrict__ XL, float* __restrict__ XR, int n,
    const float* __restrict__ Wfc, const float* __restrict__ Wfc1,
    const float* __restrict__ Wmu, const float* __restrict__ Wstd,
    short* __restrict__ WBF, int nbE, int nbW, int nbG) {
  __shared__ float sx[32][65];
  int b = blockIdx.x;
  if (b < nbE) {
    int e = b * 256 + threadIdx.x;
    if (e < E) {
      int a = ei[e], bb = ei[E + e];
      atomicAdd(degF + bb, 1);
      atomicAdd(degR + a, 1);
    }
  } else if (b < nbE + nbW) {
    int t = (b - nbE) * 256 + threadIdx.x;
    if (t < 270336) {
      int tile = t >> 9, pos = t & 511;
      int lane = pos >> 3, j = pos & 7;
      int lr = lane & 15, lg = lane >> 4;
      float v;
      if (tile < 256) {
        int nt = tile >> 3, kk = tile & 7;
        v = Wfc[(nt * 16 + lr) * 256 + kk * 32 + lg * 8 + j];
      } else if (tile < 512) {
        int t2 = tile - 256;
        int nt = t2 >> 4, kk = t2 & 15;
        v = Wfc1[(nt * 16 + lr) * 512 + kk * 32 + lg * 8 + j];
      } else {
        int t3 = tile - 512;
        int nt = t3 >> 3, kk = t3 & 7;
        int r = nt * 16 + lr;
        int col = kk * 32 + lg * 8 + j;
        v = (r < 16) ? Wmu[r * 256 + col] : Wstd[(r - 16) * 256 + col];
      }
      WBF[t] = f2bf(v);
    }
  } else {
    // layer-3 node gemm: [x|nd] @ (Wl3|Wr3)^T -> XL/XR [n,128]
    int r = b - nbE - nbW;
    int sel = (r >= nbG) ? 1 : 0;
    int bx = r - sel * nbG;
    const float* __restrict__ W = sel ? Wr3 : Wl3;
    float* __restrict__ out = sel ? XR : XL;
    const int row0 = bx * 32;
    const int tid = threadIdx.x;
    for (int i = tid; i < 32 * 64; i += 256) {
      int rr = i >> 6, c = i & 63;
      int row = row0 + rr;
      float v = 0.f;
      if (row < n) v = (c < 63) ? x[row * 63 + c] : nd[row];
      sx[rr][c] = v;
    }
    __syncthreads();
    const int nl = tid & 31;
    const int fg = tid >> 5;
    const int row = row0 + nl;
    if (row >= n) return;
    for (int i = 0; i < 16; i++) {
      int f = fg * 16 + i;
      const float* __restrict__ wrow = W + (size_t)f * 64;
      float acc = 0.f;
      #pragma unroll
      for (int k = 0; k < 64; k += 4) {
        float4 wv = *(const float4*)(wrow + k);
        acc += sx[nl][k] * wv.x + sx[nl][k + 1] * wv.y
             + sx[nl][k + 2] * wv.z + sx[nl][k + 3] * wv.w;
      }
      out[(size_t)row * 128 + f] = acc;
    }
  }
}

// ============ parallel scan (2 blocks x 1024 threads, one per direction) ============
__global__ __launch_bounds__(1024) void k_scan2(const int* __restrict__ degF,
    int* __restrict__ startF, int* __restrict__ curF, int* __restrict__ csrF,
    const int* __restrict__ degR, int* __restrict__ startR, int* __restrict__ curR,
    int* __restrict__ csrR, int n) {
  const int* __restrict__ deg = blockIdx.x ? degR : degF;
  int* __restrict__ start = blockIdx.x ? startR : startF;
  int* __restrict__ cur   = blockIdx.x ? curR : curF;
  int* __restrict__ csr   = blockIdx.x ? csrR : csrF;
  __shared__ int wsum[16];
  int t = threadIdx.x;
  int chunk = (n + 1023) >> 10;
  int lo = t * chunk; if (lo > n) lo = n;
  int hi = lo + chunk; if (hi > n) hi = n;
  int s = 0;
  for (int i = lo; i < hi; i++) s += deg[i] + 1;
  int lane = t & 63, wv = t >> 6;
  int inc = s;
  #pragma unroll
  for (int o = 1; o < 64; o <<= 1) {
    int v = __shfl_up(inc, o, 64);
    if (lane >= o) inc += v;
  }
  if (lane == 63) wsum[wv] = inc;
  __syncthreads();
  if (t < 64) {
    int v = (t < 16) ? wsum[t] : 0;
    #pragma unroll
    for (int o = 1; o < 16; o <<= 1) {
      int u = __shfl_up(v, o, 64);
      if (t >= o) v += u;
    }
    if (t < 16) wsum[t] = v;      // inclusive per-wave prefix
  }
  __syncthreads();
  int base = (wv ? wsum[wv - 1] : 0) + (inc - s);
  if (t == 0) start[n] = wsum[15];
  int acc = base;
  for (int i = lo; i < hi; i++) {
    start[i] = acc; cur[i] = acc;
    acc += deg[i] + 1;
    csr[acc - 1] = i;             // self-loop slot at segment end
  }
}

__global__ __launch_bounds__(256) void k_scatter(const int* __restrict__ ei,
    int* __restrict__ curF, int* __restrict__ curR,
    int* __restrict__ csrF, int* __restrict__ csrR, int E) {
  int e = blockIdx.x * 256 + threadIdx.x;
  if (e >= E) return;
  int a = ei[e], b = ei[E + e];
  int pf = atomicAdd(curF + b, 1); csrF[pf] = a;
  int pr = atomicAdd(curR + a, 1); csrR[pr] = b;
}

// ============ node gemm ============
template<int K, int F>
__global__ __launch_bounds__(256) void k_node_gemm(const float* __restrict__ in,
    const float* __restrict__ Wl, const float* __restrict__ Wr,
    float* __restrict__ xl, float* __restrict__ xr, int n) {
  __shared__ float sx[32][K + 1];
  const int row0 = blockIdx.x * 32;
  const float* __restrict__ W = blockIdx.y ? Wr : Wl;
  float* __restrict__ out = blockIdx.y ? xr : xl;
  const int tid = threadIdx.x;
  for (int i = tid; i < 32 * K; i += 256) {
    int r = i / K, c = i - r * K;
    sx[r][c] = (row0 + r < n) ? in[(size_t)(row0 + r) * K + c] : 0.f;
  }
  __syncthreads();
  const int nl = tid & 31;
  const int fg = tid >> 5;
  const int row = row0 + nl;
  if (row >= n) return;
  constexpr int FP = F / 8;
  for (int i = 0; i < FP; i++) {
    int f = fg * FP + i;
    const float* __restrict__ wrow = W + (size_t)f * K;
    float acc = 0.f;
    #pragma unroll
    for (int k = 0; k < K; k += 4) {
      float4 wv = *(const float4*)(wrow + k);
      acc += sx[nl][k] * wv.x + sx[nl][k + 1] * wv.y
           + sx[nl][k + 2] * wv.z + sx[nl][k + 3] * wv.w;
    }
    out[(size_t)row * F + f] = acc;
  }
}

// ============ fused GATv2 edge pass, 4 feat/thread, 2 neighbors/iter ============
// OM: 0 = f32 out only, 1 = f32 + bf16(SBF), 2 = bf16(SBF) only
template<int HF, int C, int OM>
__global__ __launch_bounds__(256) void k_gat_fused(const float* __restrict__ XL,
    const float* __restrict__ XR, const float* __restrict__ att,
    const float* __restrict__ bias, const int* __restrict__ start,
    const int* __restrict__ csr, float* __restrict__ out,
    short* __restrict__ sout, int scol, int n) {
  constexpr int G = HF / 4;
  constexpr int DPB = 256 / G;
  int d = blockIdx.x * DPB + threadIdx.x / G;
  if (d >= n) return;
  int f4 = threadIdx.x & (G - 1);
  float4 xr = *(const float4*)(XR + (size_t)d * HF + f4 * 4);
  float4 av = *(const float4*)(att + f4 * 4);
  float4 bv = *(const float4*)(bias + f4 * 4);
  float m = -INFINITY, den = 0.f;
  float4 acc = {0.f, 0.f, 0.f, 0.f};
  int j0 = start[d], j1 = start[d + 1];   // deg >= 1 always (self loop)

  auto score = [&](const float4& xl) {
    float e0 = xl.x + xr.x; e0 = e0 > 0.f ? e0 : LRELU_S * e0;
    float e1 = xl.y + xr.y; e1 = e1 > 0.f ? e1 : LRELU_S * e1;
    float e2 = xl.z + xr.z; e2 = e2 > 0.f ? e2 : LRELU_S * e2;
    float e3 = xl.w + xr.w; e3 = e3 > 0.f ? e3 : LRELU_S * e3;
    float p = av.x * e0 + av.y * e1 + av.z * e2 + av.w * e3;
    #pragma unroll
    for (int o = C / 8; o > 0; o >>= 1) p += __shfl_xor(p, o, 64);
    return p;
  };

  int j = j0;
  for (; j + 1 < j1; j += 2) {
    int sa = csr[j], sb = csr[j + 1];
    float4 xla = *(const float4*)(XL + (size_t)sa * HF + f4 * 4);
    float4 xlb = *(const float4*)(XL + (size_t)sb * HF + f4 * 4);
    float sca = score(xla);
    float scb = score(xlb);
    float mn = fmaxf(fmaxf(m, sca), scb);      // v_max3
    float scale = __expf(m - mn);
    float pa = __expf(sca - mn);
    float pb = __expf(scb - mn);
    den = den * scale + pa + pb;
    acc.x = acc.x * scale + pa * xla.x + pb * xlb.x;
    acc.y = acc.y * scale + pa * xla.y + pb * xlb.y;
    acc.z = acc.z * scale + pa * xla.z + pb * xlb.z;
    acc.w = acc.w * scale + pa * xla.w + pb * xlb.w;
    m = mn;
  }
  if (j < j1) {
    int s = csr[j];
    float4 xl = *(const float4*)(XL + (size_t)s * HF + f4 * 4);
    float sc = score(xl);
    float mn = fmaxf(m, sc);
    float scale = __expf(m - mn);
    float p = __expf(sc - mn);
    den = den * scale + p;
    acc.x = acc.x * scale + p * xl.x;
    acc.y = acc.y * scale + p * xl.y;
    acc.z = acc.z * scale + p * xl.z;
    acc.w = acc.w * scale + p * xl.w;
    m = mn;
  }
  float inv = frcp(den + 1e-16f);
  float4 o4;
  o4.x = lrelu(acc.x * inv + bv.x);
  o4.y = lrelu(acc.y * inv + bv.y);
  o4.z = lrelu(acc.z * inv + bv.z);
  o4.w = lrelu(acc.w * inv + bv.w);
  if (OM != 2) *(float4*)(out + (size_t)d * HF + f4 * 4) = o4;
  if (OM != 0) {
    union { short s[4]; int2 v; } u;
    u.s[0] = f2bf(o4.x); u.s[1] = f2bf(o4.y);
    u.s[2] = f2bf(o4.z); u.s[3] = f2bf(o4.w);
    *(int2*)(sout + (size_t)d * 128 + scol + f4 * 4) = u.v;
  }
}

// ============ fused MLP head: 64 edges / block, 512 threads, chunked H1 ============
__device__ __forceinline__ short8 lds_frag(const char* base, int row, int strideB, int k0, int lg) {
  int off = row * strideB + (((k0 * 2) + lg * 16) ^ swzb(row));
  return *(const short8*)(base + off);
}

__global__ __launch_bounds__(512, 4) void k_head(
    const short* __restrict__ SBF, const short* __restrict__ WBF,
    const int* __restrict__ ei, const float* __restrict__ epsg,
    const float* __restrict__ b_fc, const float* __restrict__ b_fc1,
    const float* __restrict__ b_mu, const float* __restrict__ b_std,
    float* __restrict__ out, double* __restrict__ LP, int E) {
  __shared__ __align__(16) char lX[32768];    // X [64][256] bf16 swizzled; later H2
  __shared__ __align__(16) char cbuf[16384];  // H1 chunk [64][128] bf16; later lMS/lred
  float* lMS  = (float*)cbuf;                 // [64*32]
  float* lred = (float*)(cbuf + 8192);        // [8]

  const int tid = threadIdx.x;
  const int eg0 = blockIdx.x * 64;

  for (int q = tid; q < 2048; q += 512) {
    int le = q >> 5, c = q & 31;
    int eg = eg0 + le;
    int node = (c < 16) ? ei[eg] : ei[E + eg];
    const short* srcp = SBF + (size_t)node * 128 + (c & 15) * 8;
    int4 v = *(const int4*)srcp;
    int col = (c * 16) ^ swzb(le);
    *(int4*)(lX + le * 512 + col) = v;
  }
  __syncthreads();

  const int w = tid >> 6, lane = tid & 63;
  const int lr = lane & 15, lg = lane >> 4;
  const floatx4 zero = {0.f, 0.f, 0.f, 0.f};

  floatx4 acc2[2][4];
  #pragma unroll
  for (int a = 0; a < 2; a++)
    #pragma unroll
    for (int b = 0; b < 4; b++) acc2[a][b] = zero;

  for (int c = 0; c < 4; c++) {
    floatx4 acc1[4];
    #pragma unroll
    for (int mi = 0; mi < 4; mi++) acc1[mi] = zero;
    for (int kk = 0; kk < 8; kk++) {
      int tile = (c * 8 + w) * 8 + kk;
      short8 b = *(const short8*)(WBF + tile * 512 + lane * 8);
      #pragma unroll
      for (int mi = 0; mi < 4; mi++) {
        short8 a = lds_frag(lX, mi * 16 + lr, 512, kk * 32, lg);
        acc1[mi] = __builtin_amdgcn_mfma_f32_16x16x32_bf16(a, b, acc1[mi], 0, 0, 0);
      }
    }
    __syncthreads();
    {
      int cl = w * 16 + lr;
      float bv = b_fc[c * 128 + cl];
      #pragma unroll
      for (int mi = 0; mi < 4; mi++)
        #pragma unroll
        for (int j = 0; j < 4; j++) {
          int row = mi * 16 + lg * 4 + j;
          float v = acc1[mi][j] + bv;
          v = v > 0.f ? v : 0.f;
          *(short*)(cbuf + row * 256 + ((cl * 2) ^ swzb(row))) = f2bf(v);
        }
    }
    __syncthreads();

    for (int kk2 = 0; kk2 < 4; kk2++) {
      short8 a[4];
      #pragma unroll
      for (int mi = 0; mi < 4; mi++) a[mi] = lds_frag(cbuf, mi * 16 + lr, 256, kk2 * 32, lg);
      #pragma unroll
      for (int ni2 = 0; ni2 < 2; ni2++) {
        int tile = 256 + (2 * w + ni2) * 16 + (c * 4 + kk2);
        short8 b = *(const short8*)(WBF + tile * 512 + lane * 8);
        #pragma unroll
        for (int mi = 0; mi < 4; mi++)
          acc2[ni2][mi] = __builtin_amdgcn_mfma_f32_16x16x32_bf16(a[mi], b, acc2[ni2][mi], 0, 0, 0);
      }
    }
  }
  __syncthreads();

  #pragma unroll
  for (int ni2 = 0; ni2 < 2; ni2++) {
    int n = (2 * w + ni2) * 16 + lr;
    float bv = b_fc1[n];
    #pragma unroll
    for (int mi = 0; mi < 4; mi++)
      #pragma unroll
      for (int j = 0; j < 4; j++) {
        int row = mi * 16 + lg * 4 + j;
        float v = acc2[ni2][mi][j] + bv;
        v = v > 0.f ? v : 0.f;
        *(short*)(lX + row * 512 + ((n * 2) ^ swzb(row))) = f2bf(v);
      }
  }
  __syncthreads();

  {
    const int mfr = w >> 1, nfr = w & 1;
    floatx4 acc3 = zero;
    for (int kk = 0; kk < 8; kk++) {
      short8 a = lds_frag(lX, mfr * 16 + lr, 512, kk * 32, lg);
      int tile = 512 + nfr * 8 + kk;
      short8 b = *(const short8*)(WBF + tile * 512 + lane * 8);
      acc3 = __builtin_amdgcn_mfma_f32_16x16x32_bf16(a, b, acc3, 0, 0, 0);
    }
    int coln = nfr * 16 + lr;
    float bv = (coln < 16) ? b_mu[coln] : b_std[coln - 16];
    #pragma unroll
    for (int j = 0; j < 4; j++) {
      int row = mfr * 16 + lg * 4 + j;
      lMS[row * 32 + coln] = acc3[j] + bv;
    }
  }
  __syncthreads();

  float lpsum = 0.f;
  #pragma unroll
  for (int it = 0; it < 2; it++) {
    int idx = tid + it * 512;
    int m = idx >> 4, g = idx & 15;
    float mu = lMS[m * 32 + g];
    float sr = lMS[m * 32 + 16 + g];
    float sd = (sr > 20.f) ? sr : __logf(1.f + __expf(sr));
    int eg = eg0 + m;
    float ep = epsg[(size_t)eg * 16 + g];
    float action = mu + sd * ep;
    float ra = ftanh(action);
    out[(size_t)eg * 16 + g] = ra;
    lpsum += -0.5f * ep * ep - __logf(sd) - HALF_LOG_2PI - __logf(1.f - ra * ra + 1e-7f);
  }
  #pragma unroll
  for (int o = 32; o > 0; o >>= 1) lpsum += __shfl_xor(lpsum, o, 64);
  if (lane == 0) lred[w] = lpsum;
  __syncthreads();
  if (tid == 0) {
    double ssum = 0.0;
    #pragma unroll
    for (int i = 0; i < 8; i++) ssum += (double)lred[i];
    atomicAdd(LP, ssum);
  }
}

__global__ void k_finalize(const double* __restrict__ LP, float* __restrict__ out, int pos) {
  out[pos] = (float)(*LP);
}

// =====================================================================
extern "C" void kernel_launch(void* const* d_in, const int* in_sizes, int n_in,
                              void* d_out, int out_size, void* d_ws, size_t ws_size,
                              hipStream_t stream) {
  const float* x    = (const float*)d_in[0];
  const float* nd   = (const float*)d_in[1];
  const int*   ei   = (const int*)d_in[2];
  const float* epsg = (const float*)d_in[3];
  const float* Wl3 = (const float*)d_in[4];  const float* Wr3 = (const float*)d_in[5];
  const float* att3 = (const float*)d_in[6]; const float* b3 = (const float*)d_in[7];
  const float* Wl4 = (const float*)d_in[8];  const float* Wr4 = (const float*)d_in[9];
  const float* att4 = (const float*)d_in[10]; const float* b4 = (const float*)d_in[11];
  const float* Wl1 = (const float*)d_in[12]; const float* Wr1 = (const float*)d_in[13];
  const float* att1 = (const float*)d_in[14]; const float* b1 = (const float*)d_in[15];
  const float* Wl2 = (const float*)d_in[16]; const float* Wr2 = (const float*)d_in[17];
  const float* att2 = (const float*)d_in[18]; const float* b2 = (const float*)d_in[19];
  const float* W_fc  = (const float*)d_in[20]; const float* b_fc  = (const float*)d_in[21];
  const float* W_fc1 = (const float*)d_in[22]; const float* b_fc1 = (const float*)d_in[23];
  const float* W_mu  = (const float*)d_in[24]; const float* b_mu  = (const float*)d_in[25];
  const float* W_std = (const float*)d_in[26]; const float* b_std = (const float*)d_in[27];

  const int N = in_sizes[0] / 63;
  const int E = in_sizes[2] / 2;
  const int E2 = E + N;
  const size_t NN = (size_t)N;

  char* base = (char*)d_ws;
  auto alloc = [&](size_t bytes) { char* p = base; base += (bytes + 15) & ~(size_t)15; return p; };

  // degF, degR, LP contiguous -> single memset covers all three
  int* degF   = (int*)alloc(NN * 4);
  int* degR   = (int*)alloc(NN * 4);
  double* LPp = (double*)alloc(16);
  float* bufB = (float*)alloc(NN * 128 * 4);
  float* XL   = (float*)alloc(NN * 128 * 4);
  float* XR   = (float*)alloc(NN * 128 * 4);
  float* XBp  = (float*)alloc(NN * 64 * 4);
  int* curF   = (int*)alloc(NN * 4);
  int* curR   = (int*)alloc(NN * 4);
  int* startF = (int*)alloc((NN + 1) * 4);
  int* startR = (int*)alloc((NN + 1) * 4);
  int* csrF   = (int*)alloc((size_t)E2 * 4);
  int* csrR   = (int*)alloc((size_t)E2 * 4);
  short* SBF  = (short*)alloc(NN * 128 * 2);
  short* WBF  = (short*)alloc(270336 * 2);

  auto nb = [](int total) { return (total + 255) / 256; };
  const int nbE = nb(E), nbW = nb(270336), nbG = (N + 31) / 32;

  // zero degF+degR+LP in one shot
  hipMemsetAsync(degF, 0, NN * 8 + 16, stream);

  // fused preamble: deg | wconv | layer3 gemm ([x|nd] -> XL/XR)
  k_pre<<<nbE + nbW + 2 * nbG, 256, 0, stream>>>(ei, degF, degR, E,
      x, nd, Wl3, Wr3, XL, XR, N, W_fc, W_fc1, W_mu, W_std, WBF, nbE, nbW, nbG);
  k_scan2<<<2, 1024, 0, stream>>>(degF, startF, curF, csrF, degR, startR, curR, csrR, N);
  k_scatter<<<nbE, 256, 0, stream>>>(ei, curF, curR, csrF, csrR, E);

  // ---- gat3 (reverse): XL/XR -> bufB[N,128]
  k_gat_fused<128, 32, 0><<<(N + 7) / 8, 256, 0, stream>>>(XL, XR, att3, b3, startR, csrR, bufB, nullptr, 0, N);

  // ---- gemm4 + gat4 (reverse): bufB -> XB[N,64] (+ bf16 into SBF cols 64..127)
  { dim3 g(nbG, 2);
    k_node_gemm<128, 64><<<g, 256, 0, stream>>>(bufB, Wl4, Wr4, XL, XR, N); }
  k_gat_fused<64, 64, 1><<<(N + 15) / 16, 256, 0, stream>>>(XL, XR, att4, b4, startR, csrR, XBp, SBF, 64, N);

  // ---- gemm1 + gat1 (forward): XB -> bufB[N,128]
  { dim3 g(nbG, 2);
    k_node_gemm<64, 128><<<g, 256, 0, stream>>>(XBp, Wl1, Wr1, XL, XR, N); }
  k_gat_fused<128, 32, 0><<<(N + 7) / 8, 256, 0, stream>>>(XL, XR, att1, b1, startF, csrF, bufB, nullptr, 0, N);

  // ---- gemm2 + gat2 (forward): bufB -> bf16 SBF cols 0..63 only
  { dim3 g(nbG, 2);
    k_node_gemm<128, 64><<<g, 256, 0, stream>>>(bufB, Wl2, Wr2, XL, XR, N); }
  k_gat_fused<64, 64, 2><<<(N + 15) / 16, 256, 0, stream>>>(XL, XR, att2, b2, startF, csrF, nullptr, SBF, 0, N);

  // ---- head + finalize
  k_head<<<E / 64, 512, 0, stream>>>(SBF, WBF, ei, epsg, b_fc, b_fc1, b_mu, b_std,
                                     (float*)d_out, LPp, E);
  k_finalize<<<1, 1, 0, stream>>>(LPp, (float*)d_out, E * 16);
}

// Round 13
// 429.520 us; speedup vs baseline: 1.2057x; 1.0028x over previous
//
#include <hip/hip_runtime.h>
#include <hip/hip_bf16.h>
#include <math.h>

typedef __attribute__((ext_vector_type(8))) short short8;
typedef __attribute__((ext_vector_type(4))) float floatx4;

#define LRELU_S 0.2f
#define HALF_LOG_2PI 0.91893853320467274178f

__device__ __forceinline__ short f2bf(float f) {
  union { float f; unsigned u; } x; x.f = f;
  unsigned r = x.u + 0x7FFFu + ((x.u >> 16) & 1u);
  return (short)(r >> 16);
}
__device__ __forceinline__ float lrelu(float v) { return v > 0.f ? v : LRELU_S * v; }
__device__ __forceinline__ float frcp(float v) { return __builtin_amdgcn_rcpf(v); }
__device__ __forceinline__ float ftanh(float x) {
  float e = __expf(2.f * x);
  return 1.f - 2.f * frcp(e + 1.f);
}
__device__ __forceinline__ int swzb(int row) {
  return ((((row >> 2) & 3) << 1) | (row & 1)) << 4;
}

// ============ fused preamble: deg-count | wconv | layer3 node-gemm ============
__global__ __launch_bounds__(256) void k_pre(const int* __restrict__ ei,
    int* __restrict__ degF, int* __restrict__ degR, int E,
    const float* __restrict__ x, const float* __restrict__ nd,
    const float* __restrict__ Wl3, const float* __restrict__ Wr3,
    float* __restrict__ XL, float* __restrict__ XR, int n,
    const float* __restrict__ Wfc, const float* __restrict__ Wfc1,
    const float* __restrict__ Wmu, const float* __restrict__ Wstd,
    short* __restrict__ WBF, int nbE, int nbW, int nbG) {
  __shared__ float sx[32][65];
  int b = blockIdx.x;
  if (b < nbE) {
    int e = b * 256 + threadIdx.x;
    if (e < E) {
      int a = ei[e], bb = ei[E + e];
      atomicAdd(degF + bb, 1);
      atomicAdd(degR + a, 1);
    }
  } else if (b < nbE + nbW) {
    int t = (b - nbE) * 256 + threadIdx.x;
    if (t < 270336) {
      int tile = t >> 9, pos = t & 511;
      int lane = pos >> 3, j = pos & 7;
      int lr = lane & 15, lg = lane >> 4;
      float v;
      if (tile < 256) {
        int nt = tile >> 3, kk = tile & 7;
        v = Wfc[(nt * 16 + lr) * 256 + kk * 32 + lg * 8 + j];
      } else if (tile < 512) {
        int t2 = tile - 256;
        int nt = t2 >> 4, kk = t2 & 15;
        v = Wfc1[(nt * 16 + lr) * 512 + kk * 32 + lg * 8 + j];
      } else {
        int t3 = tile - 512;
        int nt = t3 >> 3, kk = t3 & 7;
        int r = nt * 16 + lr;
        int col = kk * 32 + lg * 8 + j;
        v = (r < 16) ? Wmu[r * 256 + col] : Wstd[(r - 16) * 256 + col];
      }
      WBF[t] = f2bf(v);
    }
  } else {
    // layer-3 node gemm: [x|nd] @ (Wl3|Wr3)^T -> XL/XR [n,128]
    int r = b - nbE - nbW;
    int sel = (r >= nbG) ? 1 : 0;
    int bx = r - sel * nbG;
    const float* __restrict__ W = sel ? Wr3 : Wl3;
    float* __restrict__ out = sel ? XR : XL;
    const int row0 = bx * 32;
    const int tid = threadIdx.x;
    for (int i = tid; i < 32 * 64; i += 256) {
      int rr = i >> 6, c = i & 63;
      int row = row0 + rr;
      float v = 0.f;
      if (row < n) v = (c < 63) ? x[row * 63 + c] : nd[row];
      sx[rr][c] = v;
    }
    __syncthreads();
    const int nl = tid & 31;
    const int fg = tid >> 5;
    const int row = row0 + nl;
    if (row >= n) return;
    for (int i = 0; i < 16; i++) {
      int f = fg * 16 + i;
      const float* __restrict__ wrow = W + (size_t)f * 64;
      float acc = 0.f;
      #pragma unroll
      for (int k = 0; k < 64; k += 4) {
        float4 wv = *(const float4*)(wrow + k);
        acc += sx[nl][k] * wv.x + sx[nl][k + 1] * wv.y
             + sx[nl][k + 2] * wv.z + sx[nl][k + 3] * wv.w;
      }
      out[(size_t)row * 128 + f] = acc;
    }
  }
}

// ============ parallel scan (2 blocks x 1024 threads, one per direction) ============
__global__ __launch_bounds__(1024) void k_scan2(const int* __restrict__ degF,
    int* __restrict__ startF, int* __restrict__ curF, int* __restrict__ csrF,
    const int* __restrict__ degR, int* __restrict__ startR, int* __restrict__ curR,
    int* __restrict__ csrR, int n) {
  const int* __restrict__ deg = blockIdx.x ? degR : degF;
  int* __restrict__ start = blockIdx.x ? startR : startF;
  int* __restrict__ cur   = blockIdx.x ? curR : curF;
  int* __restrict__ csr   = blockIdx.x ? csrR : csrF;
  __shared__ int wsum[16];
  int t = threadIdx.x;
  int chunk = (n + 1023) >> 10;
  int lo = t * chunk; if (lo > n) lo = n;
  int hi = lo + chunk; if (hi > n) hi = n;
  int s = 0;
  for (int i = lo; i < hi; i++) s += deg[i] + 1;
  int lane = t & 63, wv = t >> 6;
  int inc = s;
  #pragma unroll
  for (int o = 1; o < 64; o <<= 1) {
    int v = __shfl_up(inc, o, 64);
    if (lane >= o) inc += v;
  }
  if (lane == 63) wsum[wv] = inc;
  __syncthreads();
  if (t < 64) {
    int v = (t < 16) ? wsum[t] : 0;
    #pragma unroll
    for (int o = 1; o < 16; o <<= 1) {
      int u = __shfl_up(v, o, 64);
      if (t >= o) v += u;
    }
    if (t < 16) wsum[t] = v;      // inclusive per-wave prefix
  }
  __syncthreads();
  int base = (wv ? wsum[wv - 1] : 0) + (inc - s);
  if (t == 0) start[n] = wsum[15];
  int acc = base;
  for (int i = lo; i < hi; i++) {
    start[i] = acc; cur[i] = acc;
    acc += deg[i] + 1;
    csr[acc - 1] = i;             // self-loop slot at segment end
  }
}

__global__ __launch_bounds__(256) void k_scatter(const int* __restrict__ ei,
    int* __restrict__ curF, int* __restrict__ curR,
    int* __restrict__ csrF, int* __restrict__ csrR, int E) {
  int e = blockIdx.x * 256 + threadIdx.x;
  if (e >= E) return;
  int a = ei[e], b = ei[E + e];
  int pf = atomicAdd(curF + b, 1); csrF[pf] = a;
  int pr = atomicAdd(curR + a, 1); csrR[pr] = b;
}

// ============ node gemm ============
template<int K, int F>
__global__ __launch_bounds__(256) void k_node_gemm(const float* __restrict__ in,
    const float* __restrict__ Wl, const float* __restrict__ Wr,
    float* __restrict__ xl, float* __restrict__ xr, int n) {
  __shared__ float sx[32][K + 1];
  const int row0 = blockIdx.x * 32;
  const float* __restrict__ W = blockIdx.y ? Wr : Wl;
  float* __restrict__ out = blockIdx.y ? xr : xl;
  const int tid = threadIdx.x;
  for (int i = tid; i < 32 * K; i += 256) {
    int r = i / K, c = i - r * K;
    sx[r][c] = (row0 + r < n) ? in[(size_t)(row0 + r) * K + c] : 0.f;
  }
  __syncthreads();
  const int nl = tid & 31;
  const int fg = tid >> 5;
  const int row = row0 + nl;
  if (row >= n) return;
  constexpr int FP = F / 8;
  for (int i = 0; i < FP; i++) {
    int f = fg * FP + i;
    const float* __restrict__ wrow = W + (size_t)f * K;
    float acc = 0.f;
    #pragma unroll
    for (int k = 0; k < K; k += 4) {
      float4 wv = *(const float4*)(wrow + k);
      acc += sx[nl][k] * wv.x + sx[nl][k + 1] * wv.y
           + sx[nl][k + 2] * wv.z + sx[nl][k + 3] * wv.w;
    }
    out[(size_t)row * F + f] = acc;
  }
}

// ============ fused GATv2 edge pass, 4 feat/thread, 2 neighbors/iter ============
// OM: 0 = f32 out only, 1 = f32 + bf16(SBF), 2 = bf16(SBF) only
template<int HF, int C, int OM>
__global__ __launch_bounds__(256) void k_gat_fused(const float* __restrict__ XL,
    const float* __restrict__ XR, const float* __restrict__ att,
    const float* __restrict__ bias, const int* __restrict__ start,
    const int* __restrict__ csr, float* __restrict__ out,
    short* __restrict__ sout, int scol, int n) {
  constexpr int G = HF / 4;
  constexpr int DPB = 256 / G;
  int d = blockIdx.x * DPB + threadIdx.x / G;
  if (d >= n) return;
  int f4 = threadIdx.x & (G - 1);
  float4 xr = *(const float4*)(XR + (size_t)d * HF + f4 * 4);
  float4 av = *(const float4*)(att + f4 * 4);
  float4 bv = *(const float4*)(bias + f4 * 4);
  float m = -INFINITY, den = 0.f;
  float4 acc = {0.f, 0.f, 0.f, 0.f};
  int j0 = start[d], j1 = start[d + 1];   // deg >= 1 always (self loop)

  auto score = [&](const float4& xl) {
    float e0 = xl.x + xr.x; e0 = e0 > 0.f ? e0 : LRELU_S * e0;
    float e1 = xl.y + xr.y; e1 = e1 > 0.f ? e1 : LRELU_S * e1;
    float e2 = xl.z + xr.z; e2 = e2 > 0.f ? e2 : LRELU_S * e2;
    float e3 = xl.w + xr.w; e3 = e3 > 0.f ? e3 : LRELU_S * e3;
    float p = av.x * e0 + av.y * e1 + av.z * e2 + av.w * e3;
    #pragma unroll
    for (int o = C / 8; o > 0; o >>= 1) p += __shfl_xor(p, o, 64);
    return p;
  };

  int j = j0;
  for (; j + 1 < j1; j += 2) {
    int sa = csr[j], sb = csr[j + 1];
    float4 xla = *(const float4*)(XL + (size_t)sa * HF + f4 * 4);
    float4 xlb = *(const float4*)(XL + (size_t)sb * HF + f4 * 4);
    float sca = score(xla);
    float scb = score(xlb);
    float mn = fmaxf(fmaxf(m, sca), scb);      // v_max3
    float scale = __expf(m - mn);
    float pa = __expf(sca - mn);
    float pb = __expf(scb - mn);
    den = den * scale + pa + pb;
    acc.x = acc.x * scale + pa * xla.x + pb * xlb.x;
    acc.y = acc.y * scale + pa * xla.y + pb * xlb.y;
    acc.z = acc.z * scale + pa * xla.z + pb * xlb.z;
    acc.w = acc.w * scale + pa * xla.w + pb * xlb.w;
    m = mn;
  }
  if (j < j1) {
    int s = csr[j];
    float4 xl = *(const float4*)(XL + (size_t)s * HF + f4 * 4);
    float sc = score(xl);
    float mn = fmaxf(m, sc);
    float scale = __expf(m - mn);
    float p = __expf(sc - mn);
    den = den * scale + p;
    acc.x = acc.x * scale + p * xl.x;
    acc.y = acc.y * scale + p * xl.y;
    acc.z = acc.z * scale + p * xl.z;
    acc.w = acc.w * scale + p * xl.w;
    m = mn;
  }
  float inv = frcp(den + 1e-16f);
  float4 o4;
  o4.x = lrelu(acc.x * inv + bv.x);
  o4.y = lrelu(acc.y * inv + bv.y);
  o4.z = lrelu(acc.z * inv + bv.z);
  o4.w = lrelu(acc.w * inv + bv.w);
  if (OM != 2) *(float4*)(out + (size_t)d * HF + f4 * 4) = o4;
  if (OM != 0) {
    union { short s[4]; int2 v; } u;
    u.s[0] = f2bf(o4.x); u.s[1] = f2bf(o4.y);
    u.s[2] = f2bf(o4.z); u.s[3] = f2bf(o4.w);
    *(int2*)(sout + (size_t)d * 128 + scol + f4 * 4) = u.v;
  }
}

// ============ fused MLP head: 64 edges / block, 512 threads, chunked H1,
// double-buffered chunk buffer -> 1 barrier per chunk ============
__device__ __forceinline__ short8 lds_frag(const char* base, int row, int strideB, int k0, int lg) {
  int off = row * strideB + (((k0 * 2) + lg * 16) ^ swzb(row));
  return *(const short8*)(base + off);
}

__global__ __launch_bounds__(512, 4) void k_head(
    const short* __restrict__ SBF, const short* __restrict__ WBF,
    const int* __restrict__ ei, const float* __restrict__ epsg,
    const float* __restrict__ b_fc, const float* __restrict__ b_fc1,
    const float* __restrict__ b_mu, const float* __restrict__ b_std,
    float* __restrict__ out, double* __restrict__ LP, int E) {
  __shared__ __align__(16) char lX[32768];   // X [64][256] bf16 swizzled; later H2
  __shared__ __align__(16) char cb0[16384];  // H1 chunk ping; later lMS/lred
  __shared__ __align__(16) char cb1[16384];  // H1 chunk pong
  float* lMS  = (float*)cb0;                 // [64*32]
  float* lred = (float*)(cb0 + 8192);        // [8]

  const int tid = threadIdx.x;
  const int eg0 = blockIdx.x * 64;

  for (int q = tid; q < 2048; q += 512) {
    int le = q >> 5, c = q & 31;
    int eg = eg0 + le;
    int node = (c < 16) ? ei[eg] : ei[E + eg];
    const short* srcp = SBF + (size_t)node * 128 + (c & 15) * 8;
    int4 v = *(const int4*)srcp;
    int col = (c * 16) ^ swzb(le);
    *(int4*)(lX + le * 512 + col) = v;
  }
  __syncthreads();

  const int w = tid >> 6, lane = tid & 63;
  const int lr = lane & 15, lg = lane >> 4;
  const floatx4 zero = {0.f, 0.f, 0.f, 0.f};

  floatx4 acc2[2][4];
  #pragma unroll
  for (int a = 0; a < 2; a++)
    #pragma unroll
    for (int b = 0; b < 4; b++) acc2[a][b] = zero;

  for (int c = 0; c < 4; c++) {
    char* cb = (c & 1) ? cb1 : cb0;
    // ---- layer-1 partial: H1 chunk cols [c*128, c*128+128)
    floatx4 acc1[4];
    #pragma unroll
    for (int mi = 0; mi < 4; mi++) acc1[mi] = zero;
    for (int kk = 0; kk < 8; kk++) {
      int tile = (c * 8 + w) * 8 + kk;
      short8 b = *(const short8*)(WBF + tile * 512 + lane * 8);
      #pragma unroll
      for (int mi = 0; mi < 4; mi++) {
        short8 a = lds_frag(lX, mi * 16 + lr, 512, kk * 32, lg);
        acc1[mi] = __builtin_amdgcn_mfma_f32_16x16x32_bf16(a, b, acc1[mi], 0, 0, 0);
      }
    }
    // epilogue -> cb[c&1]; safe: cb[c&1]'s readers (chunk c-2) finished before
    // barrier(c-1), which this wave has already passed.
    {
      int cl = w * 16 + lr;
      float bv = b_fc[c * 128 + cl];
      #pragma unroll
      for (int mi = 0; mi < 4; mi++)
        #pragma unroll
        for (int j = 0; j < 4; j++) {
          int row = mi * 16 + lg * 4 + j;
          float v = acc1[mi][j] + bv;
          v = v > 0.f ? v : 0.f;
          *(short*)(cb + row * 256 + ((cl * 2) ^ swzb(row))) = f2bf(v);
        }
    }
    __syncthreads();   // single barrier per chunk: writes visible, reads follow

    // ---- layer-2 partial accumulate from cb[c&1]
    for (int kk2 = 0; kk2 < 4; kk2++) {
      short8 a[4];
      #pragma unroll
      for (int mi = 0; mi < 4; mi++) a[mi] = lds_frag(cb, mi * 16 + lr, 256, kk2 * 32, lg);
      #pragma unroll
      for (int ni2 = 0; ni2 < 2; ni2++) {
        int tile = 256 + (2 * w + ni2) * 16 + (c * 4 + kk2);
        short8 b = *(const short8*)(WBF + tile * 512 + lane * 8);
        #pragma unroll
        for (int mi = 0; mi < 4; mi++)
          acc2[ni2][mi] = __builtin_amdgcn_mfma_f32_16x16x32_bf16(a[mi], b, acc2[ni2][mi], 0, 0, 0);
      }
    }
  }

  // ---- H2 = relu(acc2 + b_fc1) -> lX. Safe without a barrier: all lX reads
  // (layer-1 chunk 3) completed before barrier(3), already passed by every wave.
  #pragma unroll
  for (int ni2 = 0; ni2 < 2; ni2++) {
    int n = (2 * w + ni2) * 16 + lr;
    float bv = b_fc1[n];
    #pragma unroll
    for (int mi = 0; mi < 4; mi++)
      #pragma unroll
      for (int j = 0; j < 4; j++) {
        int row = mi * 16 + lg * 4 + j;
        float v = acc2[ni2][mi][j] + bv;
        v = v > 0.f ? v : 0.f;
        *(short*)(lX + row * 512 + ((n * 2) ^ swzb(row))) = f2bf(v);
      }
  }
  __syncthreads();

  // ---- layer 3: H2[64,256] @ Wms^T -> MS[64,32]
  {
    const int mfr = w >> 1, nfr = w & 1;
    floatx4 acc3 = zero;
    for (int kk = 0; kk < 8; kk++) {
      short8 a = lds_frag(lX, mfr * 16 + lr, 512, kk * 32, lg);
      int tile = 512 + nfr * 8 + kk;
      short8 b = *(const short8*)(WBF + tile * 512 + lane * 8);
      acc3 = __builtin_amdgcn_mfma_f32_16x16x32_bf16(a, b, acc3, 0, 0, 0);
    }
    int coln = nfr * 16 + lr;
    float bv = (coln < 16) ? b_mu[coln] : b_std[coln - 16];
    #pragma unroll
    for (int j = 0; j < 4; j++) {
      int row = mfr * 16 + lg * 4 + j;
      lMS[row * 32 + coln] = acc3[j] + bv;   // cb0 overlay: last cb0 read was chunk 2
    }
  }
  __syncthreads();

  float lpsum = 0.f;
  #pragma unroll
  for (int it = 0; it < 2; it++) {
    int idx = tid + it * 512;
    int m = idx >> 4, g = idx & 15;
    float mu = lMS[m * 32 + g];
    float sr = lMS[m * 32 + 16 + g];
    float sd = (sr > 20.f) ? sr : __logf(1.f + __expf(sr));
    int eg = eg0 + m;
    float ep = epsg[(size_t)eg * 16 + g];
    float action = mu + sd * ep;
    float ra = ftanh(action);
    out[(size_t)eg * 16 + g] = ra;
    lpsum += -0.5f * ep * ep - __logf(sd) - HALF_LOG_2PI - __logf(1.f - ra * ra + 1e-7f);
  }
  #pragma unroll
  for (int o = 32; o > 0; o >>= 1) lpsum += __shfl_xor(lpsum, o, 64);
  if (lane == 0) lred[w] = lpsum;
  __syncthreads();
  if (tid == 0) {
    double ssum = 0.0;
    #pragma unroll
    for (int i = 0; i < 8; i++) ssum += (double)lred[i];
    atomicAdd(LP, ssum);
  }
}

__global__ void k_finalize(const double* __restrict__ LP, float* __restrict__ out, int pos) {
  out[pos] = (float)(*LP);
}

// =====================================================================
extern "C" void kernel_launch(void* const* d_in, const int* in_sizes, int n_in,
                              void* d_out, int out_size, void* d_ws, size_t ws_size,
                              hipStream_t stream) {
  const float* x    = (const float*)d_in[0];
  const float* nd   = (const float*)d_in[1];
  const int*   ei   = (const int*)d_in[2];
  const float* epsg = (const float*)d_in[3];
  const float* Wl3 = (const float*)d_in[4];  const float* Wr3 = (const float*)d_in[5];
  const float* att3 = (const float*)d_in[6]; const float* b3 = (const float*)d_in[7];
  const float* Wl4 = (const float*)d_in[8];  const float* Wr4 = (const float*)d_in[9];
  const float* att4 = (const float*)d_in[10]; const float* b4 = (const float*)d_in[11];
  const float* Wl1 = (const float*)d_in[12]; const float* Wr1 = (const float*)d_in[13];
  const float* att1 = (const float*)d_in[14]; const float* b1 = (const float*)d_in[15];
  const float* Wl2 = (const float*)d_in[16]; const float* Wr2 = (const float*)d_in[17];
  const float* att2 = (const float*)d_in[18]; const float* b2 = (const float*)d_in[19];
  const float* W_fc  = (const float*)d_in[20]; const float* b_fc  = (const float*)d_in[21];
  const float* W_fc1 = (const float*)d_in[22]; const float* b_fc1 = (const float*)d_in[23];
  const float* W_mu  = (const float*)d_in[24]; const float* b_mu  = (const float*)d_in[25];
  const float* W_std = (const float*)d_in[26]; const float* b_std = (const float*)d_in[27];

  const int N = in_sizes[0] / 63;
  const int E = in_sizes[2] / 2;
  const int E2 = E + N;
  const size_t NN = (size_t)N;

  char* base = (char*)d_ws;
  auto alloc = [&](size_t bytes) { char* p = base; base += (bytes + 15) & ~(size_t)15; return p; };

  // degF, degR, LP contiguous -> single memset covers all three
  int* degF   = (int*)alloc(NN * 4);
  int* degR   = (int*)alloc(NN * 4);
  double* LPp = (double*)alloc(16);
  float* bufB = (float*)alloc(NN * 128 * 4);
  float* XL   = (float*)alloc(NN * 128 * 4);
  float* XR   = (float*)alloc(NN * 128 * 4);
  float* XBp  = (float*)alloc(NN * 64 * 4);
  int* curF   = (int*)alloc(NN * 4);
  int* curR   = (int*)alloc(NN * 4);
  int* startF = (int*)alloc((NN + 1) * 4);
  int* startR = (int*)alloc((NN + 1) * 4);
  int* csrF   = (int*)alloc((size_t)E2 * 4);
  int* csrR   = (int*)alloc((size_t)E2 * 4);
  short* SBF  = (short*)alloc(NN * 128 * 2);
  short* WBF  = (short*)alloc(270336 * 2);

  auto nb = [](int total) { return (total + 255) / 256; };
  const int nbE = nb(E), nbW = nb(270336), nbG = (N + 31) / 32;

  // zero degF+degR+LP in one shot
  hipMemsetAsync(degF, 0, NN * 8 + 16, stream);

  // fused preamble: deg | wconv | layer3 gemm ([x|nd] -> XL/XR)
  k_pre<<<nbE + nbW + 2 * nbG, 256, 0, stream>>>(ei, degF, degR, E,
      x, nd, Wl3, Wr3, XL, XR, N, W_fc, W_fc1, W_mu, W_std, WBF, nbE, nbW, nbG);
  k_scan2<<<2, 1024, 0, stream>>>(degF, startF, curF, csrF, degR, startR, curR, csrR, N);
  k_scatter<<<nbE, 256, 0, stream>>>(ei, curF, curR, csrF, csrR, E);

  // ---- gat3 (reverse): XL/XR -> bufB[N,128]
  k_gat_fused<128, 32, 0><<<(N + 7) / 8, 256, 0, stream>>>(XL, XR, att3, b3, startR, csrR, bufB, nullptr, 0, N);

  // ---- gemm4 + gat4 (reverse): bufB -> XB[N,64] (+ bf16 into SBF cols 64..127)
  { dim3 g(nbG, 2);
    k_node_gemm<128, 64><<<g, 256, 0, stream>>>(bufB, Wl4, Wr4, XL, XR, N); }
  k_gat_fused<64, 64, 1><<<(N + 15) / 16, 256, 0, stream>>>(XL, XR, att4, b4, startR, csrR, XBp, SBF, 64, N);

  // ---- gemm1 + gat1 (forward): XB -> bufB[N,128]
  { dim3 g(nbG, 2);
    k_node_gemm<64, 128><<<g, 256, 0, stream>>>(XBp, Wl1, Wr1, XL, XR, N); }
  k_gat_fused<128, 32, 0><<<(N + 7) / 8, 256, 0, stream>>>(XL, XR, att1, b1, startF, csrF, bufB, nullptr, 0, N);

  // ---- gemm2 + gat2 (forward): bufB -> bf16 SBF cols 0..63 only
  { dim3 g(nbG, 2);
    k_node_gemm<128, 64><<<g, 256, 0, stream>>>(bufB, Wl2, Wr2, XL, XR, N); }
  k_gat_fused<64, 64, 2><<<(N + 15) / 16, 256, 0, stream>>>(XL, XR, att2, b2, startF, csrF, nullptr, SBF, 0, N);

  // ---- head + finalize
  k_head<<<E / 64, 512, 0, stream>>>(SBF, WBF, ei, epsg, b_fc, b_fc1, b_mu, b_std,
                                     (float*)d_out, LPp, E);
  k_finalize<<<1, 1, 0, stream>>>(LPp, (float*)d_out, E * 16);
}

// Round 14
// 420.901 us; speedup vs baseline: 1.2303x; 1.0205x over previous
//
#include <hip/hip_runtime.h>
#include <hip/hip_bf16.h>
#include <math.h>

typedef __attribute__((ext_vector_type(8))) short short8;
typedef __attribute__((ext_vector_type(4))) float floatx4;

#define LRELU_S 0.2f
#define HALF_LOG_2PI 0.91893853320467274178f

__device__ __forceinline__ short f2bf(float f) {
  union { float f; unsigned u; } x; x.f = f;
  unsigned r = x.u + 0x7FFFu + ((x.u >> 16) & 1u);
  return (short)(r >> 16);
}
__device__ __forceinline__ float lrelu(float v) { return v > 0.f ? v : LRELU_S * v; }
__device__ __forceinline__ float frcp(float v) { return __builtin_amdgcn_rcpf(v); }
__device__ __forceinline__ float ftanh(float x) {
  float e = __expf(2.f * x);
  return 1.f - 2.f * frcp(e + 1.f);
}
__device__ __forceinline__ int swzb(int row) {
  return ((((row >> 2) & 3) << 1) | (row & 1)) << 4;
}

// ============ fused preamble: deg-count | wconv | layer3 node-gemm ============
__global__ __launch_bounds__(256) void k_pre(const int* __restrict__ ei,
    int* __restrict__ degF, int* __restrict__ degR, int E,
    const float* __restrict__ x, const float* __restrict__ nd,
    const float* __restrict__ Wl3, const float* __restrict__ Wr3,
    float* __restrict__ XL, float* __restrict__ XR, int n,
    const float* __restrict__ Wfc, const float* __restrict__ Wfc1,
    const float* __restrict__ Wmu, const float* __restrict__ Wstd,
    short* __restrict__ WBF, int nbE, int nbW, int nbG) {
  __shared__ float sx[32][65];
  int b = blockIdx.x;
  if (b < nbE) {
    int e = b * 256 + threadIdx.x;
    if (e < E) {
      int a = ei[e], bb = ei[E + e];
      atomicAdd(degF + bb, 1);
      atomicAdd(degR + a, 1);
    }
  } else if (b < nbE + nbW) {
    int t = (b - nbE) * 256 + threadIdx.x;
    if (t < 270336) {
      int tile = t >> 9, pos = t & 511;
      int lane = pos >> 3, j = pos & 7;
      int lr = lane & 15, lg = lane >> 4;
      float v;
      if (tile < 256) {
        int nt = tile >> 3, kk = tile & 7;
        v = Wfc[(nt * 16 + lr) * 256 + kk * 32 + lg * 8 + j];
      } else if (tile < 512) {
        int t2 = tile - 256;
        int nt = t2 >> 4, kk = t2 & 15;
        v = Wfc1[(nt * 16 + lr) * 512 + kk * 32 + lg * 8 + j];
      } else {
        int t3 = tile - 512;
        int nt = t3 >> 3, kk = t3 & 7;
        int r = nt * 16 + lr;
        int col = kk * 32 + lg * 8 + j;
        v = (r < 16) ? Wmu[r * 256 + col] : Wstd[(r - 16) * 256 + col];
      }
      WBF[t] = f2bf(v);
    }
  } else {
    // layer-3 node gemm: [x|nd] @ (Wl3|Wr3)^T -> XL/XR [n,128]
    int r = b - nbE - nbW;
    int sel = (r >= nbG) ? 1 : 0;
    int bx = r - sel * nbG;
    const float* __restrict__ W = sel ? Wr3 : Wl3;
    float* __restrict__ out = sel ? XR : XL;
    const int row0 = bx * 32;
    const int tid = threadIdx.x;
    for (int i = tid; i < 32 * 64; i += 256) {
      int rr = i >> 6, c = i & 63;
      int row = row0 + rr;
      float v = 0.f;
      if (row < n) v = (c < 63) ? x[row * 63 + c] : nd[row];
      sx[rr][c] = v;
    }
    __syncthreads();
    const int nl = tid & 31;
    const int fg = tid >> 5;
    const int row = row0 + nl;
    if (row >= n) return;
    for (int i = 0; i < 16; i++) {
      int f = fg * 16 + i;
      const float* __restrict__ wrow = W + (size_t)f * 64;
      float acc = 0.f;
      #pragma unroll
      for (int k = 0; k < 64; k += 4) {
        float4 wv = *(const float4*)(wrow + k);
        acc += sx[nl][k] * wv.x + sx[nl][k + 1] * wv.y
             + sx[nl][k + 2] * wv.z + sx[nl][k + 3] * wv.w;
      }
      out[(size_t)row * 128 + f] = acc;
    }
  }
}

// ============ parallel scan (2 blocks x 1024 threads, one per direction) ============
__global__ __launch_bounds__(1024) void k_scan2(const int* __restrict__ degF,
    int* __restrict__ startF, int* __restrict__ curF, int* __restrict__ csrF,
    const int* __restrict__ degR, int* __restrict__ startR, int* __restrict__ curR,
    int* __restrict__ csrR, int n) {
  const int* __restrict__ deg = blockIdx.x ? degR : degF;
  int* __restrict__ start = blockIdx.x ? startR : startF;
  int* __restrict__ cur   = blockIdx.x ? curR : curF;
  int* __restrict__ csr   = blockIdx.x ? csrR : csrF;
  __shared__ int wsum[16];
  int t = threadIdx.x;
  int chunk = (n + 1023) >> 10;
  int lo = t * chunk; if (lo > n) lo = n;
  int hi = lo + chunk; if (hi > n) hi = n;
  int s = 0;
  for (int i = lo; i < hi; i++) s += deg[i] + 1;
  int lane = t & 63, wv = t >> 6;
  int inc = s;
  #pragma unroll
  for (int o = 1; o < 64; o <<= 1) {
    int v = __shfl_up(inc, o, 64);
    if (lane >= o) inc += v;
  }
  if (lane == 63) wsum[wv] = inc;
  __syncthreads();
  if (t < 64) {
    int v = (t < 16) ? wsum[t] : 0;
    #pragma unroll
    for (int o = 1; o < 16; o <<= 1) {
      int u = __shfl_up(v, o, 64);
      if (t >= o) v += u;
    }
    if (t < 16) wsum[t] = v;      // inclusive per-wave prefix
  }
  __syncthreads();
  int base = (wv ? wsum[wv - 1] : 0) + (inc - s);
  if (t == 0) start[n] = wsum[15];
  int acc = base;
  for (int i = lo; i < hi; i++) {
    start[i] = acc; cur[i] = acc;
    acc += deg[i] + 1;
    csr[acc - 1] = i;             // self-loop slot at segment end
  }
}

__global__ __launch_bounds__(256) void k_scatter(const int* __restrict__ ei,
    int* __restrict__ curF, int* __restrict__ curR,
    int* __restrict__ csrF, int* __restrict__ csrR, int E) {
  int e = blockIdx.x * 256 + threadIdx.x;
  if (e >= E) return;
  int a = ei[e], b = ei[E + e];
  int pf = atomicAdd(curF + b, 1); csrF[pf] = a;
  int pr = atomicAdd(curR + a, 1); csrR[pr] = b;
}

// ============ node gemm ============
template<int K, int F>
__global__ __launch_bounds__(256) void k_node_gemm(const float* __restrict__ in,
    const float* __restrict__ Wl, const float* __restrict__ Wr,
    float* __restrict__ xl, float* __restrict__ xr, int n) {
  __shared__ float sx[32][K + 1];
  const int row0 = blockIdx.x * 32;
  const float* __restrict__ W = blockIdx.y ? Wr : Wl;
  float* __restrict__ out = blockIdx.y ? xr : xl;
  const int tid = threadIdx.x;
  for (int i = tid; i < 32 * K; i += 256) {
    int r = i / K, c = i - r * K;
    sx[r][c] = (row0 + r < n) ? in[(size_t)(row0 + r) * K + c] : 0.f;
  }
  __syncthreads();
  const int nl = tid & 31;
  const int fg = tid >> 5;
  const int row = row0 + nl;
  if (row >= n) return;
  constexpr int FP = F / 8;
  for (int i = 0; i < FP; i++) {
    int f = fg * FP + i;
    const float* __restrict__ wrow = W + (size_t)f * K;
    float acc = 0.f;
    #pragma unroll
    for (int k = 0; k < K; k += 4) {
      float4 wv = *(const float4*)(wrow + k);
      acc += sx[nl][k] * wv.x + sx[nl][k + 1] * wv.y
           + sx[nl][k + 2] * wv.z + sx[nl][k + 3] * wv.w;
    }
    out[(size_t)row * F + f] = acc;
  }
}

// ============ fused GATv2 edge pass, 4 feat/thread, 4 neighbors/iter ============
// OM: 0 = f32 out only, 1 = f32 + bf16(SBF), 2 = bf16(SBF) only
template<int HF, int C, int OM>
__global__ __launch_bounds__(256) void k_gat_fused(const float* __restrict__ XL,
    const float* __restrict__ XR, const float* __restrict__ att,
    const float* __restrict__ bias, const int* __restrict__ start,
    const int* __restrict__ csr, float* __restrict__ out,
    short* __restrict__ sout, int scol, int n) {
  constexpr int G = HF / 4;
  constexpr int DPB = 256 / G;
  int d = blockIdx.x * DPB + threadIdx.x / G;
  if (d >= n) return;
  int f4 = threadIdx.x & (G - 1);
  float4 xr = *(const float4*)(XR + (size_t)d * HF + f4 * 4);
  float4 av = *(const float4*)(att + f4 * 4);
  float4 bv = *(const float4*)(bias + f4 * 4);
  float m = -INFINITY, den = 0.f;
  float4 acc = {0.f, 0.f, 0.f, 0.f};
  int j0 = start[d], j1 = start[d + 1];   // deg >= 1 always (self loop)

  auto score = [&](const float4& xl) {
    float e0 = xl.x + xr.x; e0 = e0 > 0.f ? e0 : LRELU_S * e0;
    float e1 = xl.y + xr.y; e1 = e1 > 0.f ? e1 : LRELU_S * e1;
    float e2 = xl.z + xr.z; e2 = e2 > 0.f ? e2 : LRELU_S * e2;
    float e3 = xl.w + xr.w; e3 = e3 > 0.f ? e3 : LRELU_S * e3;
    float p = av.x * e0 + av.y * e1 + av.z * e2 + av.w * e3;
    #pragma unroll
    for (int o = C / 8; o > 0; o >>= 1) p += __shfl_xor(p, o, 64);
    return p;
  };

  int j = j0;
  // 4-wide loop: 4 loads in flight, 4 ILP'd score reductions, 5 indep exps,
  // 1 rescale per 4 neighbors — shortens the serial online-softmax chain.
  for (; j + 3 < j1; j += 4) {
    int s0 = csr[j], s1 = csr[j + 1], s2 = csr[j + 2], s3 = csr[j + 3];
    float4 x0 = *(const float4*)(XL + (size_t)s0 * HF + f4 * 4);
    float4 x1 = *(const float4*)(XL + (size_t)s1 * HF + f4 * 4);
    float4 x2 = *(const float4*)(XL + (size_t)s2 * HF + f4 * 4);
    float4 x3 = *(const float4*)(XL + (size_t)s3 * HF + f4 * 4);
    float c0 = score(x0);
    float c1 = score(x1);
    float c2 = score(x2);
    float c3 = score(x3);
    float mn = fmaxf(fmaxf(m, fmaxf(c0, c1)), fmaxf(c2, c3));
    float scale = __expf(m - mn);
    float p0 = __expf(c0 - mn);
    float p1 = __expf(c1 - mn);
    float p2 = __expf(c2 - mn);
    float p3 = __expf(c3 - mn);
    den = den * scale + ((p0 + p1) + (p2 + p3));
    acc.x = acc.x * scale + (p0 * x0.x + p1 * x1.x) + (p2 * x2.x + p3 * x3.x);
    acc.y = acc.y * scale + (p0 * x0.y + p1 * x1.y) + (p2 * x2.y + p3 * x3.y);
    acc.z = acc.z * scale + (p0 * x0.z + p1 * x1.z) + (p2 * x2.z + p3 * x3.z);
    acc.w = acc.w * scale + (p0 * x0.w + p1 * x1.w) + (p2 * x2.w + p3 * x3.w);
    m = mn;
  }
  for (; j < j1; j++) {
    int s = csr[j];
    float4 xl = *(const float4*)(XL + (size_t)s * HF + f4 * 4);
    float sc = score(xl);
    float mn = fmaxf(m, sc);
    float scale = __expf(m - mn);
    float p = __expf(sc - mn);
    den = den * scale + p;
    acc.x = acc.x * scale + p * xl.x;
    acc.y = acc.y * scale + p * xl.y;
    acc.z = acc.z * scale + p * xl.z;
    acc.w = acc.w * scale + p * xl.w;
    m = mn;
  }
  float inv = frcp(den + 1e-16f);
  float4 o4;
  o4.x = lrelu(acc.x * inv + bv.x);
  o4.y = lrelu(acc.y * inv + bv.y);
  o4.z = lrelu(acc.z * inv + bv.z);
  o4.w = lrelu(acc.w * inv + bv.w);
  if (OM != 2) *(float4*)(out + (size_t)d * HF + f4 * 4) = o4;
  if (OM != 0) {
    union { short s[4]; int2 v; } u;
    u.s[0] = f2bf(o4.x); u.s[1] = f2bf(o4.y);
    u.s[2] = f2bf(o4.z); u.s[3] = f2bf(o4.w);
    *(int2*)(sout + (size_t)d * 128 + scol + f4 * 4) = u.v;
  }
}

// ============ fused MLP head: 64 edges / block, 512 threads, chunked H1,
// double-buffered chunk buffer -> 1 barrier per chunk ============
__device__ __forceinline__ short8 lds_frag(const char* base, int row, int strideB, int k0, int lg) {
  int off = row * strideB + (((k0 * 2) + lg * 16) ^ swzb(row));
  return *(const short8*)(base + off);
}

__global__ __launch_bounds__(512, 4) void k_head(
    const short* __restrict__ SBF, const short* __restrict__ WBF,
    const int* __restrict__ ei, const float* __restrict__ epsg,
    const float* __restrict__ b_fc, const float* __restrict__ b_fc1,
    const float* __restrict__ b_mu, const float* __restrict__ b_std,
    float* __restrict__ out, double* __restrict__ LP, int E) {
  __shared__ __align__(16) char lX[32768];   // X [64][256] bf16 swizzled; later H2
  __shared__ __align__(16) char cb0[16384];  // H1 chunk ping; later lMS/lred
  __shared__ __align__(16) char cb1[16384];  // H1 chunk pong
  float* lMS  = (float*)cb0;                 // [64*32]
  float* lred = (float*)(cb0 + 8192);        // [8]

  const int tid = threadIdx.x;
  const int eg0 = blockIdx.x * 64;

  for (int q = tid; q < 2048; q += 512) {
    int le = q >> 5, c = q & 31;
    int eg = eg0 + le;
    int node = (c < 16) ? ei[eg] : ei[E + eg];
    const short* srcp = SBF + (size_t)node * 128 + (c & 15) * 8;
    int4 v = *(const int4*)srcp;
    int col = (c * 16) ^ swzb(le);
    *(int4*)(lX + le * 512 + col) = v;
  }
  __syncthreads();

  const int w = tid >> 6, lane = tid & 63;
  const int lr = lane & 15, lg = lane >> 4;
  const floatx4 zero = {0.f, 0.f, 0.f, 0.f};

  floatx4 acc2[2][4];
  #pragma unroll
  for (int a = 0; a < 2; a++)
    #pragma unroll
    for (int b = 0; b < 4; b++) acc2[a][b] = zero;

  for (int c = 0; c < 4; c++) {
    char* cb = (c & 1) ? cb1 : cb0;
    floatx4 acc1[4];
    #pragma unroll
    for (int mi = 0; mi < 4; mi++) acc1[mi] = zero;
    for (int kk = 0; kk < 8; kk++) {
      int tile = (c * 8 + w) * 8 + kk;
      short8 b = *(const short8*)(WBF + tile * 512 + lane * 8);
      #pragma unroll
      for (int mi = 0; mi < 4; mi++) {
        short8 a = lds_frag(lX, mi * 16 + lr, 512, kk * 32, lg);
        acc1[mi] = __builtin_amdgcn_mfma_f32_16x16x32_bf16(a, b, acc1[mi], 0, 0, 0);
      }
    }
    {
      int cl = w * 16 + lr;
      float bv = b_fc[c * 128 + cl];
      #pragma unroll
      for (int mi = 0; mi < 4; mi++)
        #pragma unroll
        for (int j = 0; j < 4; j++) {
          int row = mi * 16 + lg * 4 + j;
          float v = acc1[mi][j] + bv;
          v = v > 0.f ? v : 0.f;
          *(short*)(cb + row * 256 + ((cl * 2) ^ swzb(row))) = f2bf(v);
        }
    }
    __syncthreads();   // single barrier per chunk

    for (int kk2 = 0; kk2 < 4; kk2++) {
      short8 a[4];
      #pragma unroll
      for (int mi = 0; mi < 4; mi++) a[mi] = lds_frag(cb, mi * 16 + lr, 256, kk2 * 32, lg);
      #pragma unroll
      for (int ni2 = 0; ni2 < 2; ni2++) {
        int tile = 256 + (2 * w + ni2) * 16 + (c * 4 + kk2);
        short8 b = *(const short8*)(WBF + tile * 512 + lane * 8);
        #pragma unroll
        for (int mi = 0; mi < 4; mi++)
          acc2[ni2][mi] = __builtin_amdgcn_mfma_f32_16x16x32_bf16(a[mi], b, acc2[ni2][mi], 0, 0, 0);
      }
    }
  }

  #pragma unroll
  for (int ni2 = 0; ni2 < 2; ni2++) {
    int n = (2 * w + ni2) * 16 + lr;
    float bv = b_fc1[n];
    #pragma unroll
    for (int mi = 0; mi < 4; mi++)
      #pragma unroll
      for (int j = 0; j < 4; j++) {
        int row = mi * 16 + lg * 4 + j;
        float v = acc2[ni2][mi][j] + bv;
        v = v > 0.f ? v : 0.f;
        *(short*)(lX + row * 512 + ((n * 2) ^ swzb(row))) = f2bf(v);
      }
  }
  __syncthreads();

  {
    const int mfr = w >> 1, nfr = w & 1;
    floatx4 acc3 = zero;
    for (int kk = 0; kk < 8; kk++) {
      short8 a = lds_frag(lX, mfr * 16 + lr, 512, kk * 32, lg);
      int tile = 512 + nfr * 8 + kk;
      short8 b = *(const short8*)(WBF + tile * 512 + lane * 8);
      acc3 = __builtin_amdgcn_mfma_f32_16x16x32_bf16(a, b, acc3, 0, 0, 0);
    }
    int coln = nfr * 16 + lr;
    float bv = (coln < 16) ? b_mu[coln] : b_std[coln - 16];
    #pragma unroll
    for (int j = 0; j < 4; j++) {
      int row = mfr * 16 + lg * 4 + j;
      lMS[row * 32 + coln] = acc3[j] + bv;
    }
  }
  __syncthreads();

  float lpsum = 0.f;
  #pragma unroll
  for (int it = 0; it < 2; it++) {
    int idx = tid + it * 512;
    int m = idx >> 4, g = idx & 15;
    float mu = lMS[m * 32 + g];
    float sr = lMS[m * 32 + 16 + g];
    float sd = (sr > 20.f) ? sr : __logf(1.f + __expf(sr));
    int eg = eg0 + m;
    float ep = epsg[(size_t)eg * 16 + g];
    float action = mu + sd * ep;
    float ra = ftanh(action);
    out[(size_t)eg * 16 + g] = ra;
    lpsum += -0.5f * ep * ep - __logf(sd) - HALF_LOG_2PI - __logf(1.f - ra * ra + 1e-7f);
  }
  #pragma unroll
  for (int o = 32; o > 0; o >>= 1) lpsum += __shfl_xor(lpsum, o, 64);
  if (lane == 0) lred[w] = lpsum;
  __syncthreads();
  if (tid == 0) {
    double ssum = 0.0;
    #pragma unroll
    for (int i = 0; i < 8; i++) ssum += (double)lred[i];
    atomicAdd(LP, ssum);
  }
}

__global__ void k_finalize(const double* __restrict__ LP, float* __restrict__ out, int pos) {
  out[pos] = (float)(*LP);
}

// =====================================================================
extern "C" void kernel_launch(void* const* d_in, const int* in_sizes, int n_in,
                              void* d_out, int out_size, void* d_ws, size_t ws_size,
                              hipStream_t stream) {
  const float* x    = (const float*)d_in[0];
  const float* nd   = (const float*)d_in[1];
  const int*   ei   = (const int*)d_in[2];
  const float* epsg = (const float*)d_in[3];
  const float* Wl3 = (const float*)d_in[4];  const float* Wr3 = (const float*)d_in[5];
  const float* att3 = (const float*)d_in[6]; const float* b3 = (const float*)d_in[7];
  const float* Wl4 = (const float*)d_in[8];  const float* Wr4 = (const float*)d_in[9];
  const float* att4 = (const float*)d_in[10]; const float* b4 = (const float*)d_in[11];
  const float* Wl1 = (const float*)d_in[12]; const float* Wr1 = (const float*)d_in[13];
  const float* att1 = (const float*)d_in[14]; const float* b1 = (const float*)d_in[15];
  const float* Wl2 = (const float*)d_in[16]; const float* Wr2 = (const float*)d_in[17];
  const float* att2 = (const float*)d_in[18]; const float* b2 = (const float*)d_in[19];
  const float* W_fc  = (const float*)d_in[20]; const float* b_fc  = (const float*)d_in[21];
  const float* W_fc1 = (const float*)d_in[22]; const float* b_fc1 = (const float*)d_in[23];
  const float* W_mu  = (const float*)d_in[24]; const float* b_mu  = (const float*)d_in[25];
  const float* W_std = (const float*)d_in[26]; const float* b_std = (const float*)d_in[27];

  const int N = in_sizes[0] / 63;
  const int E = in_sizes[2] / 2;
  const int E2 = E + N;
  const size_t NN = (size_t)N;

  char* base = (char*)d_ws;
  auto alloc = [&](size_t bytes) { char* p = base; base += (bytes + 15) & ~(size_t)15; return p; };

  // degF, degR, LP contiguous -> single memset covers all three
  int* degF   = (int*)alloc(NN * 4);
  int* degR   = (int*)alloc(NN * 4);
  double* LPp = (double*)alloc(16);
  float* bufB = (float*)alloc(NN * 128 * 4);
  float* XL   = (float*)alloc(NN * 128 * 4);
  float* XR   = (float*)alloc(NN * 128 * 4);
  float* XBp  = (float*)alloc(NN * 64 * 4);
  int* curF   = (int*)alloc(NN * 4);
  int* curR   = (int*)alloc(NN * 4);
  int* startF = (int*)alloc((NN + 1) * 4);
  int* startR = (int*)alloc((NN + 1) * 4);
  int* csrF   = (int*)alloc((size_t)E2 * 4);
  int* csrR   = (int*)alloc((size_t)E2 * 4);
  short* SBF  = (short*)alloc(NN * 128 * 2);
  short* WBF  = (short*)alloc(270336 * 2);

  auto nb = [](int total) { return (total + 255) / 256; };
  const int nbE = nb(E), nbW = nb(270336), nbG = (N + 31) / 32;

  // zero degF+degR+LP in one shot
  hipMemsetAsync(degF, 0, NN * 8 + 16, stream);

  // fused preamble: deg | wconv | layer3 gemm ([x|nd] -> XL/XR)
  k_pre<<<nbE + nbW + 2 * nbG, 256, 0, stream>>>(ei, degF, degR, E,
      x, nd, Wl3, Wr3, XL, XR, N, W_fc, W_fc1, W_mu, W_std, WBF, nbE, nbW, nbG);
  k_scan2<<<2, 1024, 0, stream>>>(degF, startF, curF, csrF, degR, startR, curR, csrR, N);
  k_scatter<<<nbE, 256, 0, stream>>>(ei, curF, curR, csrF, csrR, E);

  // ---- gat3 (reverse): XL/XR -> bufB[N,128]
  k_gat_fused<128, 32, 0><<<(N + 7) / 8, 256, 0, stream>>>(XL, XR, att3, b3, startR, csrR, bufB, nullptr, 0, N);

  // ---- gemm4 + gat4 (reverse): bufB -> XB[N,64] (+ bf16 into SBF cols 64..127)
  { dim3 g(nbG, 2);
    k_node_gemm<128, 64><<<g, 256, 0, stream>>>(bufB, Wl4, Wr4, XL, XR, N); }
  k_gat_fused<64, 64, 1><<<(N + 15) / 16, 256, 0, stream>>>(XL, XR, att4, b4, startR, csrR, XBp, SBF, 64, N);

  // ---- gemm1 + gat1 (forward): XB -> bufB[N,128]
  { dim3 g(nbG, 2);
    k_node_gemm<64, 128><<<g, 256, 0, stream>>>(XBp, Wl1, Wr1, XL, XR, N); }
  k_gat_fused<128, 32, 0><<<(N + 7) / 8, 256, 0, stream>>>(XL, XR, att1, b1, startF, csrF, bufB, nullptr, 0, N);

  // ---- gemm2 + gat2 (forward): bufB -> bf16 SBF cols 0..63 only
  { dim3 g(nbG, 2);
    k_node_gemm<128, 64><<<g, 256, 0, stream>>>(bufB, Wl2, Wr2, XL, XR, N); }
  k_gat_fused<64, 64, 2><<<(N + 15) / 16, 256, 0, stream>>>(XL, XR, att2, b2, startF, csrF, nullptr, SBF, 0, N);

  // ---- head + finalize
  k_head<<<E / 64, 512, 0, stream>>>(SBF, WBF, ei, epsg, b_fc, b_fc1, b_mu, b_std,
                                     (float*)d_out, LPp, E);
  k_finalize<<<1, 1, 0, stream>>>(LPp, (float*)d_out, E * 16);
}